// Round 7
// baseline (243.978 us; speedup 1.0000x reference)
//
#include <hip/hip_runtime.h>
#include <hip/hip_fp16.h>

#define BB 4
#define CC 3
#define HH 384
#define WW 384
#define FF 5
#define KK 25            // FF*FF
#define HW (HH*WW)

#define TX 64            // tile width (pixels) — 32 lanes x 2 px
#define TY 8             // tile height

typedef float fx2 __attribute__((ext_vector_type(2)));

__device__ __forceinline__ fx2 nt_load2(const float* p) {
    return __builtin_nontemporal_load((const fx2*)p);
}
__device__ __forceinline__ unsigned h2bits(__half2 h) {
    return *(const unsigned int*)&h;
}

// Full-quad table: one 32B-aligned entry per (b, y0, x0) holding ALL 12
// bilinear corner values (channels c0,c1,c2 at the 4 clamped corners) as
// fp16.  Layout (dwords):
//   d0=(c0,c1)@(x0,y0)  d1=@(x1,y0)  d2=@(x0,y1)  d3=@(x1,y1)
//   d4=(c2@(x0,y0), c2@(x1,y0))      d5=(c2@(x0,y1), c2@(x1,y1))
//   d6,d7 = pad (never read)
// One tap = dwordx4 @+0 plus dwordx2 @+16 — ALWAYS the same 64B line, so
// each tap/pixel costs exactly ONE L3 line and needs zero clamp/fallback
// logic (x/y clamping is baked in at pack time).
__global__ __launch_bounds__(256) void pack_kernel(
    const float* __restrict__ inp, uint2* __restrict__ qtab)
{
    int t = blockIdx.x * blockDim.x + threadIdx.x;
    if (t >= BB * HW) return;
    int b   = t / HW;
    int rem = t - b * HW;
    int y   = rem / WW;
    int x   = rem - y * WW;
    int x1  = min(x + 1, WW - 1);
    int yn  = min(y + 1, HH - 1);
    const float* c0p = inp + (size_t)b * CC * HW;
    const float* c1p = c0p + HW;
    const float* c2p = c1p + HW;
    int o00 = y * WW + x,  o01 = y * WW + x1;
    int o10 = yn * WW + x, o11 = yn * WW + x1;
    unsigned d0 = h2bits(__floats2half2_rn(c0p[o00], c1p[o00]));
    unsigned d1 = h2bits(__floats2half2_rn(c0p[o01], c1p[o01]));
    unsigned d2 = h2bits(__floats2half2_rn(c0p[o10], c1p[o10]));
    unsigned d3 = h2bits(__floats2half2_rn(c0p[o11], c1p[o11]));
    unsigned d4 = h2bits(__floats2half2_rn(c2p[o00], c2p[o01]));
    unsigned d5 = h2bits(__floats2half2_rn(c2p[o10], c2p[o11]));
    // entry t occupies uint2 slots [4t .. 4t+3]; slot 4t+3 is pad
    uint2* e = qtab + ((size_t)t << 2);
    e[0] = make_uint2(d0, d1);
    e[1] = make_uint2(d2, d3);
    e[2] = make_uint2(d4, d5);
}

// 2 px/thread, 64x8 tile — R0's proven structure with the tap path
// reduced to: compute (y0,x0) -> ONE entry address -> 16B + 8B loads
// from the same 64B line -> 12 halves -> weighted sum.  No LDS, no
// barrier, no bounds checks, no second-row addressing.
__global__ __launch_bounds__(256) void dsepconv_kernel(
    const uint2* __restrict__ qtab,
    const float* __restrict__ vert,
    const float* __restrict__ horiz,
    const float* __restrict__ offx,
    const float* __restrict__ offy,
    const float* __restrict__ mask,
    float* __restrict__ out)
{
    int tx = threadIdx.x & 31;
    int ty = threadIdx.x >> 5;
    int xb = blockIdx.x * TX + tx * 2;      // even
    int y  = blockIdx.y * TY + ty;
    int b  = blockIdx.z;
    int planeoff = y * WW + xb;             // 8B aligned

    fx2 v2[FF], h2[FF];
#pragma unroll
    for (int f = 0; f < FF; ++f) {
        v2[f] = nt_load2(vert  + (b * FF + f) * HW + planeoff);
        h2[f] = nt_load2(horiz + (b * FF + f) * HW + planeoff);
    }

    const uint2* qt = qtab + ((size_t)b * HW << 2);

    float acc[2][3] = {{0.f,0.f,0.f},{0.f,0.f,0.f}};
    const float fy = (float)y;

    for (int ki = 0; ki < FF; ++ki) {
        float dy = fy + (float)(ki - 2);
        const float* ox_p = offx + (size_t)(b * KK + ki * FF) * HW + planeoff;
        const float* oy_p = offy + (size_t)(b * KK + ki * FF) * HW + planeoff;
        const float* m_p  = mask + (size_t)(b * KK + ki * FF) * HW + planeoff;
#pragma unroll
        for (int kj = 0; kj < FF; ++kj) {
            fx2 ox2 = nt_load2(ox_p + kj * HW);
            fx2 oy2 = nt_load2(oy_p + kj * HW);
            fx2 m2  = nt_load2(m_p  + kj * HW);
#pragma unroll
            for (int p = 0; p < 2; ++p) {
                float wt = v2[ki][p] * h2[kj][p] * m2[p];
                float py = oy2[p] + dy;
                float px = ox2[p] + (float)(xb + p + kj - 2);
                py = fminf(fmaxf(py, 0.f), (float)(HH - 1));
                px = fminf(fmaxf(px, 0.f), (float)(WW - 1));
                float y0f = floorf(py);
                float x0f = floorf(px);
                float wy = py - y0f;
                float wx = px - x0f;
                int y0 = (int)y0f;
                int x0 = (int)x0f;

                const uint2* ep = qt + ((size_t)(y0 * WW + x0) << 2);
                uint4 g  = *(const uint4*)ep;        // c0,c1 quad (16B)
                uint2 g2 = ep[2];                    // c2 quad    (8B, same line)

                float2 f00 = __half22float2(*(const __half2*)&g.x);
                float2 f01 = __half22float2(*(const __half2*)&g.y);
                float2 f10 = __half22float2(*(const __half2*)&g.z);
                float2 f11 = __half22float2(*(const __half2*)&g.w);
                float2 c2a = __half22float2(*(const __half2*)&g2.x);
                float2 c2b = __half22float2(*(const __half2*)&g2.y);

                float w00 = (1.f - wy) * (1.f - wx);
                float w01 = (1.f - wy) * wx;
                float w10 = wy * (1.f - wx);
                float w11 = wy * wx;

                acc[p][0] += wt * (f00.x*w00 + f01.x*w01 + f10.x*w10 + f11.x*w11);
                acc[p][1] += wt * (f00.y*w00 + f01.y*w01 + f10.y*w10 + f11.y*w11);
                acc[p][2] += wt * (c2a.x*w00 + c2a.y*w01 + c2b.x*w10 + c2b.y*w11);
            }
        }
    }

#pragma unroll
    for (int c = 0; c < CC; ++c) {
        fx2 o; o.x = acc[0][c]; o.y = acc[1][c];
        *(fx2*)(out + ((size_t)b * CC + c) * HW + planeoff) = o;
    }
}

extern "C" void kernel_launch(void* const* d_in, const int* in_sizes, int n_in,
                              void* d_out, int out_size, void* d_ws, size_t ws_size,
                              hipStream_t stream) {
    const float* inp   = (const float*)d_in[0];
    const float* vert  = (const float*)d_in[1];
    const float* horiz = (const float*)d_in[2];
    const float* offx  = (const float*)d_in[3];
    const float* offy  = (const float*)d_in[4];
    const float* mask  = (const float*)d_in[5];
    float* out = (float*)d_out;
    uint2* qtab = (uint2*)d_ws;   // 18.87 MB full-quad table (32B/entry)

    {
        pack_kernel<<<(BB * HW + 255) / 256, 256, 0, stream>>>(inp, qtab);
    }
    {
        dim3 grid(WW / TX, HH / TY, BB);   // 6 x 48 x 4
        dsepconv_kernel<<<grid, 256, 0, stream>>>(
            qtab, vert, horiz, offx, offy, mask, out);
    }
}